// Round 16
// baseline (4994.818 us; speedup 1.0000x reference)
//
#include <hip/hip_runtime.h>
#include <math.h>

#define BATCH  64
#define TSTEPS 2048
#define EMBED  300
#define HID    256
#define GATES  1024  // 4*HID
#define ASTR   328   // f16 stride of k_gemm staged tiles (300 data + 28 pad)

typedef __fp16 h2 __attribute__((ext_vector_type(2)));   // matches cvt_pkrtz/fdot2
typedef __fp16 h4 __attribute__((ext_vector_type(4)));
typedef __fp16 h8 __attribute__((ext_vector_type(8)));
typedef float  f4 __attribute__((ext_vector_type(4)));

__device__ __forceinline__ h2 pack_h2(float a, float b) {
    return __builtin_amdgcn_cvt_pkrtz(a, b);
}
__device__ __forceinline__ unsigned pack_u(float a, float b) {
    return __builtin_bit_cast(unsigned, __builtin_amdgcn_cvt_pkrtz(a, b));
}
__device__ __forceinline__ float rcpf_(float x) {
#if __has_builtin(__builtin_amdgcn_rcpf)
    return __builtin_amdgcn_rcpf(x);
#else
    return 1.0f / x;
#endif
}
__device__ __forceinline__ float sigm_(float x) { return rcpf_(1.f + __expf(-x)); }
__device__ __forceinline__ float tanh_(float x) { return 1.f - 2.f*rcpf_(__expf(2.f*x) + 1.f); }

// ---------------- Kernel 1: per-chunk compaction of update steps ------------
__global__ __launch_bounds__(256) void k_compact(
    const float* __restrict__ mask, const int* __restrict__ lengths,
    int* __restrict__ list, int* __restrict__ cnt,
    float* __restrict__ h_state, float* __restrict__ c_state,
    int t0, int CT, int first_chunk)
{
    int b = blockIdx.x, tid = threadIdx.x;
    if (first_chunk) {
        h_state[b*HID + tid] = 0.f;   // blockDim == HID
        c_state[b*HID + tid] = 0.f;
    }
    int idx = lengths[b] - 1;
    idx = idx < 0 ? 0 : (idx > TSTEPS-1 ? TSTEPS-1 : idx);

    __shared__ int wcnt[4];
    __shared__ int running;
    if (tid == 0) running = 0;
    __syncthreads();

    for (int base = 0; base < CT; base += 256) {
        int t = t0 + base + tid;
        bool pred = ((base + tid) < CT) && (t <= idx)
                    && (mask[b*TSTEPS + t] >= 0.5f);
        unsigned long long bal = __ballot(pred);
        int wave = tid >> 6, lane = tid & 63;
        if (lane == 0) wcnt[wave] = __popcll(bal);
        __syncthreads();
        int off = running;
        for (int w2 = 0; w2 < wave; ++w2) off += wcnt[w2];
        off += __popcll(bal & ((1ull << lane) - 1ull));
        if (pred) list[b*CT + off] = t;
        __syncthreads();
        if (tid == 0) running += wcnt[0] + wcnt[1] + wcnt[2] + wcnt[3];
        __syncthreads();
    }
    if (tid == 0) cnt[b] = running;
}

// ---------------- Kernel 2: gathered GEMM via MFMA, persistent-B ------------
// (unchanged from round 14 — verified absmax 0.0)
__global__ __launch_bounds__(256) void k_gemm(
    const float* __restrict__ emb, const float* __restrict__ W_ih,
    const int* __restrict__ list, const int* __restrict__ cnt,
    float* __restrict__ Z, int CT)
{
    int b = blockIdx.z;
    int mb = cnt[b];
    int n0 = blockIdx.x * 128;
    int tid = threadIdx.x;
    int w = tid >> 6, l = tid & 63;

    __shared__ _Float16 Al[64 * ASTR];     // 41,984 B
    __shared__ _Float16 Bl[128 * ASTR];    // 83,968 B
    __shared__ int tl[64];

    for (int idx = tid; idx < 128*75; idx += 256) {
        int r = idx / 75, c = idx - 75*r;
        float4 v = ((const float4*)(W_ih + (size_t)(n0 + r)*EMBED))[c];
        *(unsigned*)&Bl[r*ASTR + 4*c]     = pack_u(v.x, v.y);
        *(unsigned*)&Bl[r*ASTR + 4*c + 2] = pack_u(v.z, v.w);
    }
    for (int idx = tid; idx < 128*14; idx += 256) {
        int r = idx / 14, c2 = idx - 14*r;
        *(unsigned*)&Bl[r*ASTR + 300 + 2*c2] = 0u;
    }
    for (int idx = tid; idx < 64*14; idx += 256) {
        int r = idx / 14, c2 = idx - 14*r;
        *(unsigned*)&Al[r*ASTR + 300 + 2*c2] = 0u;   // pad written once
    }

    int arow = w*16 + (l & 15);
    int kg4  = (l >> 4) * 4;
    int drow0 = w*16 + (l >> 4)*4;

    for (int i0 = 0; i0 < mb; i0 += 64) {
        __syncthreads();           // prev MFMA done -> Al/tl reusable; B ready
        if (tid < 64) {
            int j = i0 + tid;
            tl[tid] = (j < mb) ? list[b*CT + j] : -1;
        }
        __syncthreads();           // tl visible
        for (int idx = tid; idx < 64*75; idx += 256) {
            int r = idx / 75, c = idx - 75*r;
            float4 v = {0.f, 0.f, 0.f, 0.f};
            int trow = tl[r];
            if (trow >= 0)
                v = ((const float4*)(emb + ((size_t)b*TSTEPS + trow)*EMBED))[c];
            *(unsigned*)&Al[r*ASTR + 4*c]     = pack_u(v.x, v.y);
            *(unsigned*)&Al[r*ASTR + 4*c + 2] = pack_u(v.z, v.w);
        }
        __syncthreads();           // Al visible

        f4 acc[8];
        #pragma unroll
        for (int nt = 0; nt < 8; ++nt) acc[nt] = f4{0.f, 0.f, 0.f, 0.f};

        #pragma unroll 2
        for (int ks = 0; ks < 10; ++ks) {
            int kb = ks*32 + kg4;
            h4 alo = *(const h4*)&Al[arow*ASTR + kb];
            h4 ahi = *(const h4*)&Al[arow*ASTR + kb + 16];
            h8 af = __builtin_shufflevector(alo, ahi, 0,1,2,3,4,5,6,7);
            #pragma unroll
            for (int nt = 0; nt < 8; ++nt) {
                int brow = nt*16 + (l & 15);
                h4 blo = *(const h4*)&Bl[brow*ASTR + kb];
                h4 bhi = *(const h4*)&Bl[brow*ASTR + kb + 16];
                h8 bf = __builtin_shufflevector(blo, bhi, 0,1,2,3,4,5,6,7);
                acc[nt] = __builtin_amdgcn_mfma_f32_16x16x32_f16(af, bf, acc[nt], 0, 0, 0);
            }
        }

        #pragma unroll
        for (int nt = 0; nt < 8; ++nt) {
            #pragma unroll
            for (int j = 0; j < 4; ++j) {
                int r = drow0 + j;
                if (i0 + r < mb)
                    Z[((size_t)b*CT + i0 + r)*GATES + n0 + nt*16 + (l & 15)] = acc[nt][j];
            }
        }
    }
}

// ---------------- Kernel 3: recurrent LSTM — MFMA matvec, W in AGPR ---------
// ONE block (512 thr, 8 waves) per batch. Wave w owns gate-rows
// [128w,128w+128). W_hh staged once as 64 h8 B-fragments/thread (256 AGPR —
// MFMA reads B from AGPR natively, no accvgpr_read per use). Per step:
// A = h in row 0 only (lanes cl==0), 2 b64 LDS reads x 8 K-steps; 64 MFMA
// per wave on the idle matrix pipe; y = D row 0 (lanes<16, reg 0) -> yl LDS;
// cell update by tid<256. DS insts/CU-step ~540 -> ~210 (the measured
// bottleneck). Fragment layouts identical to k_gemm's (HW-verified r12).
__global__ __launch_bounds__(512) void k_lstm(
    const float* __restrict__ Z, const int* __restrict__ cnt,
    const float* __restrict__ W_hh,
    const float* __restrict__ b_ih, const float* __restrict__ b_hh,
    float* __restrict__ h_state, float* __restrict__ c_state, int CT)
{
    int b   = blockIdx.x;
    int tid = threadIdx.x;       // 0..511
    int w   = tid >> 6;          // wave: rows [128w, 128w+128)
    int l   = tid & 63;
    int g   = l >> 4;            // k-group 0..3
    int cl  = l & 15;            // column within 16 (B row = output row)
    int d   = tid & 255;         // updater dim (tid<256)

    __shared__ __align__(16) _Float16 h_arr[HID];   // 512 B
    __shared__ float yl[GATES];                     // 4 KB

    // ---- stage W as MFMA B-fragments: 64 x h8 (-> 256 AGPR) ----------------
    h8 wb[64];
    #pragma unroll
    for (int f = 0; f < 64; ++f) {
        int nt = f >> 3, ks = f & 7;
        int row = 128*w + 16*nt + cl;
        const float* src = W_hh + (size_t)row*HID + ks*32 + 4*g;
        float4 lo = *(const float4*)src;
        float4 hi = *(const float4*)(src + 16);
        uint4 uu;
        uu.x = pack_u(lo.x, lo.y);
        uu.y = pack_u(lo.z, lo.w);
        uu.z = pack_u(hi.x, hi.y);
        uu.w = pack_u(hi.z, hi.w);
        wb[f] = __builtin_bit_cast(h8, uu);
    }

    // ---- updater state (tid<256): c, biases for all 4 gates ----------------
    float c_reg = 0.f, bI = 0.f, bF = 0.f, bG = 0.f, bO = 0.f;
    if (tid < 256) {
        c_reg = c_state[(size_t)b*HID + d];
        h_arr[d] = (_Float16)h_state[(size_t)b*HID + d];
        bI = b_ih[d]       + b_hh[d];
        bF = b_ih[256 + d] + b_hh[256 + d];
        bG = b_ih[512 + d] + b_hh[512 + d];
        bO = b_ih[768 + d] + b_hh[768 + d];
    }
    __syncthreads();

    int mb = cnt[b];
    float zI = 0.f, zF = 0.f, zG = 0.f, zO = 0.f;
    if (mb > 0 && tid < 256) {
        const float* zr = Z + ((size_t)b*CT)*GATES;
        zI = zr[d]; zF = zr[256 + d]; zG = zr[512 + d]; zO = zr[768 + d];
    }
    unsigned amask = (cl == 0) ? 0xFFFFFFFFu : 0u;   // A row-0 lanes only

    for (int j = 0; j < mb; ++j) {
        // prefetch next step's z (updaters) under the MFMA work
        float zIn = 0.f, zFn = 0.f, zGn = 0.f, zOn = 0.f;
        if (j + 1 < mb && tid < 256) {
            const float* zr = Z + ((size_t)b*CT + j + 1)*GATES;
            zIn = zr[d]; zFn = zr[256 + d]; zGn = zr[512 + d]; zOn = zr[768 + d];
        }

        f4 acc[8];
        #pragma unroll
        for (int nt = 0; nt < 8; ++nt) acc[nt] = f4{0.f, 0.f, 0.f, 0.f};

        #pragma unroll
        for (int ks = 0; ks < 8; ++ks) {
            int k0 = ks*32 + 4*g;
            uint2 ha = *(const uint2*)&h_arr[k0];        // broadcast (4 addrs)
            uint2 hb = *(const uint2*)&h_arr[k0 + 16];
            uint4 ua;
            ua.x = ha.x & amask; ua.y = ha.y & amask;
            ua.z = hb.x & amask; ua.w = hb.y & amask;
            h8 af = __builtin_bit_cast(h8, ua);
            #pragma unroll
            for (int nt = 0; nt < 8; ++nt)
                acc[nt] = __builtin_amdgcn_mfma_f32_16x16x32_f16(af, wb[nt*8 + ks], acc[nt], 0, 0, 0);
        }

        // D row 0 lives in lanes 0..15, reg 0; col = lane = output row offset
        if (l < 16) {
            #pragma unroll
            for (int nt = 0; nt < 8; ++nt)
                yl[128*w + 16*nt + l] = acc[nt][0];
        }
        __syncthreads();   // y complete; h_arr reads done

        if (tid < 256) {
            float aI = yl[d]       + zI + bI;
            float aF = yl[256 + d] + zF + bF;
            float aG = yl[512 + d] + zG + bG;
            float aO = yl[768 + d] + zO + bO;
            float iv = sigm_(aI), fv = sigm_(aF);
            float gv = tanh_(aG), ov = sigm_(aO);
            c_reg = fv * c_reg + iv * gv;
            float hn = ov * tanh_(c_reg);
            h_arr[d] = (_Float16)hn;
        }
        __syncthreads();   // h ready for next step
        zI = zIn; zF = zFn; zG = zGn; zO = zOn;
    }

    if (tid < 256) {
        h_state[(size_t)b*HID + d] = (float)h_arr[d];
        c_state[(size_t)b*HID + d] = c_reg;
    }
}

// ---------------- Kernel 4: logits -> softmax -> argmax ---------------------
__global__ __launch_bounds__(64) void k_final(
    const float* __restrict__ h_state, const float* __restrict__ W_out,
    const float* __restrict__ b_out, float* __restrict__ out)
{
    int b = threadIdx.x;   // 64 threads
    float l0 = b_out[0], l1 = b_out[1];
    for (int k = 0; k < HID; ++k) {
        float h = h_state[b*HID + k];
        l0 += h * W_out[k];
        l1 += h * W_out[HID + k];
    }
    float m  = fmaxf(l0, l1);
    float e0 = expf(l0 - m), e1 = expf(l1 - m);
    float s  = e0 + e1;
    float p0 = e0 / s, p1 = e1 / s;
    out[b*2 + 0] = p0;
    out[b*2 + 1] = p1;
    out[BATCH*2 + b] = (p1 > p0) ? 1.0f : 0.0f;  // argmax, first-index tiebreak
}

// ---------------- host ------------------------------------------------------
extern "C" void kernel_launch(void* const* d_in, const int* in_sizes, int n_in,
                              void* d_out, int out_size, void* d_ws, size_t ws_size,
                              hipStream_t stream)
{
    (void)in_sizes; (void)n_in; (void)out_size;
    const float* emb   = (const float*)d_in[0];
    const float* mask  = (const float*)d_in[1];
    const int*   len   = (const int*)  d_in[2];
    const float* W_ih  = (const float*)d_in[3];
    const float* W_hh  = (const float*)d_in[4];
    const float* b_ih  = (const float*)d_in[5];
    const float* b_hh  = (const float*)d_in[6];
    const float* W_out = (const float*)d_in[7];
    const float* b_out = (const float*)d_in[8];
    float* out = (float*)d_out;

    char* p = (char*)d_ws;
    auto carve = [&](size_t bytes) -> char* {
        char* r = p;
        p += (bytes + 255) & ~(size_t)255;
        return r;
    };
    float* h_state = (float*)carve((size_t)BATCH*HID*4);
    float* c_state = (float*)carve((size_t)BATCH*HID*4);
    int*   cntb    = (int*)  carve((size_t)BATCH*4);

    size_t fixed = (size_t)(p - (char*)d_ws);
    int CT = TSTEPS;  // shrink to fit workspace
    while (CT > 64) {
        size_t lb = (((size_t)BATCH*CT*4) + 255) & ~(size_t)255;
        size_t zb = (size_t)BATCH*CT*GATES*4;
        if (fixed + lb + zb + 1024 <= ws_size) break;
        CT >>= 1;
    }
    int*   list = (int*)  carve((size_t)BATCH*CT*4);
    float* Z    = (float*)carve((size_t)BATCH*CT*GATES*4);

    int nchunks = TSTEPS / CT;
    for (int c = 0; c < nchunks; ++c) {
        int t0 = c * CT;
        int first = (c == 0) ? 1 : 0;
        hipLaunchKernelGGL(k_compact, dim3(BATCH), dim3(256), 0, stream,
                           mask, len, list, cntb, h_state, c_state,
                           t0, CT, first);
        hipLaunchKernelGGL(k_gemm, dim3(8, 1, BATCH), dim3(256), 0, stream,
                           emb, W_ih, list, cntb, Z, CT);
        hipLaunchKernelGGL(k_lstm, dim3(BATCH), dim3(512), 0, stream,
                           Z, cntb, W_hh, b_ih, b_hh,
                           h_state, c_state, CT);
    }
    hipLaunchKernelGGL(k_final, dim3(1), dim3(64), 0, stream,
                       h_state, W_out, b_out, out);
}

// Round 17
// 2080.655 us; speedup vs baseline: 2.4006x; 2.4006x over previous
//
#include <hip/hip_runtime.h>
#include <math.h>

#define BATCH  64
#define TSTEPS 2048
#define EMBED  300
#define HID    256
#define GATES  1024  // 4*HID
#define WSTRIDE 36   // dwords per W-LDS row: 16B-aligned rows -> b128 reads;
                     // banks (4l+4c)%32 distinct within each 8-lane phase
#define ASTR   328   // f16 stride of k_gemm staged tiles (300 data + 28 pad)

typedef __fp16 h2 __attribute__((ext_vector_type(2)));   // matches cvt_pkrtz/fdot2
typedef __fp16 h4 __attribute__((ext_vector_type(4)));
typedef __fp16 h8 __attribute__((ext_vector_type(8)));
typedef float  f4 __attribute__((ext_vector_type(4)));

__device__ __forceinline__ h2 pack_h2(float a, float b) {
    return __builtin_amdgcn_cvt_pkrtz(a, b);
}
__device__ __forceinline__ h2 bc_h2(unsigned u) {
    return __builtin_bit_cast(h2, u);
}
__device__ __forceinline__ float dot2f(h2 w, h2 h, float acc) {
#if __has_builtin(__builtin_amdgcn_fdot2)
    return __builtin_amdgcn_fdot2(w, h, acc, false);   // f32 accumulate
#else
    return acc + (float)w[0]*(float)h[0] + (float)w[1]*(float)h[1];
#endif
}
__device__ __forceinline__ float rcpf_(float x) {
#if __has_builtin(__builtin_amdgcn_rcpf)
    return __builtin_amdgcn_rcpf(x);
#else
    return 1.0f / x;
#endif
}
__device__ __forceinline__ float sigm_(float x) { return rcpf_(1.f + __expf(-x)); }
__device__ __forceinline__ float tanh_(float x) { return 1.f - 2.f*rcpf_(__expf(2.f*x) + 1.f); }

// ---------------- Kernel 1: per-chunk compaction of update steps ------------
__global__ __launch_bounds__(256) void k_compact(
    const float* __restrict__ mask, const int* __restrict__ lengths,
    int* __restrict__ list, int* __restrict__ cnt,
    float* __restrict__ h_state, float* __restrict__ c_state,
    int t0, int CT, int first_chunk)
{
    int b = blockIdx.x, tid = threadIdx.x;
    if (first_chunk) {
        h_state[b*HID + tid] = 0.f;   // blockDim == HID
        c_state[b*HID + tid] = 0.f;
    }
    int idx = lengths[b] - 1;
    idx = idx < 0 ? 0 : (idx > TSTEPS-1 ? TSTEPS-1 : idx);

    __shared__ int wcnt[4];
    __shared__ int running;
    if (tid == 0) running = 0;
    __syncthreads();

    for (int base = 0; base < CT; base += 256) {
        int t = t0 + base + tid;
        bool pred = ((base + tid) < CT) && (t <= idx)
                    && (mask[b*TSTEPS + t] >= 0.5f);
        unsigned long long bal = __ballot(pred);
        int wave = tid >> 6, lane = tid & 63;
        if (lane == 0) wcnt[wave] = __popcll(bal);
        __syncthreads();
        int off = running;
        for (int w2 = 0; w2 < wave; ++w2) off += wcnt[w2];
        off += __popcll(bal & ((1ull << lane) - 1ull));
        if (pred) list[b*CT + off] = t;
        __syncthreads();
        if (tid == 0) running += wcnt[0] + wcnt[1] + wcnt[2] + wcnt[3];
        __syncthreads();
    }
    if (tid == 0) cnt[b] = running;
}

// ---------------- Kernel 2: gathered GEMM via MFMA, persistent-B ------------
// (unchanged from round 14 — verified absmax 0.0)
__global__ __launch_bounds__(256) void k_gemm(
    const float* __restrict__ emb, const float* __restrict__ W_ih,
    const int* __restrict__ list, const int* __restrict__ cnt,
    float* __restrict__ Z, int CT)
{
    int b = blockIdx.z;
    int mb = cnt[b];
    int n0 = blockIdx.x * 128;
    int tid = threadIdx.x;
    int w = tid >> 6, l = tid & 63;

    __shared__ _Float16 Al[64 * ASTR];     // 41,984 B
    __shared__ _Float16 Bl[128 * ASTR];    // 83,968 B
    __shared__ int tl[64];

    for (int idx = tid; idx < 128*75; idx += 256) {
        int r = idx / 75, c = idx - 75*r;
        float4 v = ((const float4*)(W_ih + (size_t)(n0 + r)*EMBED))[c];
        *(h2*)&Bl[r*ASTR + 4*c]     = pack_h2(v.x, v.y);
        *(h2*)&Bl[r*ASTR + 4*c + 2] = pack_h2(v.z, v.w);
    }
    for (int idx = tid; idx < 128*14; idx += 256) {
        int r = idx / 14, c2 = idx - 14*r;
        *(unsigned*)&Bl[r*ASTR + 300 + 2*c2] = 0u;
    }
    for (int idx = tid; idx < 64*14; idx += 256) {
        int r = idx / 14, c2 = idx - 14*r;
        *(unsigned*)&Al[r*ASTR + 300 + 2*c2] = 0u;   // pad written once
    }

    int arow = w*16 + (l & 15);
    int kg4  = (l >> 4) * 4;
    int drow0 = w*16 + (l >> 4)*4;

    for (int i0 = 0; i0 < mb; i0 += 64) {
        __syncthreads();           // prev MFMA done -> Al/tl reusable; B ready
        if (tid < 64) {
            int j = i0 + tid;
            tl[tid] = (j < mb) ? list[b*CT + j] : -1;
        }
        __syncthreads();           // tl visible
        for (int idx = tid; idx < 64*75; idx += 256) {
            int r = idx / 75, c = idx - 75*r;
            float4 v = {0.f, 0.f, 0.f, 0.f};
            int trow = tl[r];
            if (trow >= 0)
                v = ((const float4*)(emb + ((size_t)b*TSTEPS + trow)*EMBED))[c];
            *(h2*)&Al[r*ASTR + 4*c]     = pack_h2(v.x, v.y);
            *(h2*)&Al[r*ASTR + 4*c + 2] = pack_h2(v.z, v.w);
        }
        __syncthreads();           // Al visible

        f4 acc[8];
        #pragma unroll
        for (int nt = 0; nt < 8; ++nt) acc[nt] = f4{0.f, 0.f, 0.f, 0.f};

        #pragma unroll 2
        for (int ks = 0; ks < 10; ++ks) {
            int kb = ks*32 + kg4;
            h4 alo = *(const h4*)&Al[arow*ASTR + kb];
            h4 ahi = *(const h4*)&Al[arow*ASTR + kb + 16];
            h8 af = __builtin_shufflevector(alo, ahi, 0,1,2,3,4,5,6,7);
            #pragma unroll
            for (int nt = 0; nt < 8; ++nt) {
                int brow = nt*16 + (l & 15);
                h4 blo = *(const h4*)&Bl[brow*ASTR + kb];
                h4 bhi = *(const h4*)&Bl[brow*ASTR + kb + 16];
                h8 bf = __builtin_shufflevector(blo, bhi, 0,1,2,3,4,5,6,7);
                acc[nt] = __builtin_amdgcn_mfma_f32_16x16x32_f16(af, bf, acc[nt], 0, 0, 0);
            }
        }

        #pragma unroll
        for (int nt = 0; nt < 8; ++nt) {
            #pragma unroll
            for (int j = 0; j < 4; ++j) {
                int r = drow0 + j;
                if (i0 + r < mb)
                    Z[((size_t)b*CT + i0 + r)*GATES + n0 + nt*16 + (l & 15)] = acc[nt][j];
            }
        }
    }
}

// ---------------- Kernel 3: recurrent LSTM — ONE block per batch ------------
// r12 structure (the 5x-validated local optimum: 192 h2 AGPR + k<64 LDS,
// 2 barriers, native activations). ONE change: WSTRIDE 34->36 so each row's
// 16B chunk is 16B-aligned -> the c<8 W reads become 2x uint4 (b128) instead
// of 4x uint2 (b64), halving W-DS instruction count (the measured bottleneck:
// ~560 wave-DS-insts/CU-step ~ 3400cy). Banks (4l+4c)%32 are distinct within
// each 8-lane b128 service phase -> conflict-free.
__global__ __launch_bounds__(512, 2) void k_lstm(
    const float* __restrict__ Z, const int* __restrict__ cnt,
    const float* __restrict__ W_hh,
    const float* __restrict__ b_ih, const float* __restrict__ b_hh,
    float* __restrict__ h_state, float* __restrict__ c_state, int CT)
{
    int b = blockIdx.x;
    int tid = threadIdx.x;            // 0..511
    int d   = tid & 255;              // hidden dim this thread's rows act on
    int rowA = tid;                   // gate (tid>>8)      : 0 or 1
    int rowB = tid + 512;             // gate (tid>>8) + 2  : 2 or 3

    __shared__ __align__(16) unsigned wlds[1024 * WSTRIDE];  // 147,456 B
    __shared__ float act13[2][256];                  // forget, out broadcast
    __shared__ __align__(16) _Float16 h_arr[HID];    // current h (f16)

    // ---- stage W[k<64] into LDS as f16 pairs --------------------------------
    for (int idx = tid; idx < 1024*32; idx += 512) {
        int r = idx >> 5, k = idx & 31;              // k = half2 index (f16 2k,2k+1)
        float2 v = ((const float2*)(W_hh + (size_t)r*HID))[k];
        *(h2*)&wlds[r*WSTRIDE + k] = pack_h2(v.x, v.y);
    }

    // ---- W[k in 64..255] into registers: 96 half2 per row -------------------
    h2 wrA[96], wrB[96];
    {
        const float2* pA = (const float2*)(W_hh + (size_t)rowA*HID);
        const float2* pB = (const float2*)(W_hh + (size_t)rowB*HID);
        #pragma unroll
        for (int t = 0; t < 96; ++t) {
            float2 va = pA[32 + t], vb = pB[32 + t];
            wrA[t] = pack_h2(va.x, va.y);
            wrB[t] = pack_h2(vb.x, vb.y);
        }
    }
    float biasA = b_ih[rowA] + b_hh[rowA];
    float biasB = b_ih[rowB] + b_hh[rowB];

    float c_reg = 0.f;
    if (tid < 256) {
        h_arr[d] = (_Float16)h_state[(size_t)b*HID + d];
        c_reg    = c_state[(size_t)b*HID + d];
    }
    __syncthreads();

    int mb = cnt[b];
    float zAcur = 0.f, zBcur = 0.f;
    if (mb > 0) {
        zAcur = Z[((size_t)b*CT)*GATES + rowA];
        zBcur = Z[((size_t)b*CT)*GATES + rowB];
    }

    for (int j = 0; j < mb; ++j) {
        // prefetch next step's z under the dot
        float zAn = 0.f, zBn = 0.f;
        if (j + 1 < mb) {
            zAn = Z[((size_t)b*CT + j + 1)*GATES + rowA];
            zBn = Z[((size_t)b*CT + j + 1)*GATES + rowB];
        }

        float accA0 = 0.f, accA1 = 0.f, accB0 = 0.f, accB1 = 0.f;
        #pragma unroll
        for (int c = 0; c < 32; ++c) {
            uint4 hv = ((const uint4*)h_arr)[c];     // 8 f16 of h (broadcast)
            h2 h0 = bc_h2(hv.x), h1 = bc_h2(hv.y);
            h2 h2_ = bc_h2(hv.z), h3 = bc_h2(hv.w);
            h2 wA0, wA1, wA2, wA3, wB0, wB1, wB2, wB3;
            if (c < 8) {
                uint4 wa = *(const uint4*)&wlds[rowA*WSTRIDE + 4*c];   // b128
                uint4 wb = *(const uint4*)&wlds[rowB*WSTRIDE + 4*c];   // b128
                wA0 = bc_h2(wa.x); wA1 = bc_h2(wa.y);
                wA2 = bc_h2(wa.z); wA3 = bc_h2(wa.w);
                wB0 = bc_h2(wb.x); wB1 = bc_h2(wb.y);
                wB2 = bc_h2(wb.z); wB3 = bc_h2(wb.w);
            } else {
                int t = (c - 8) * 4;
                wA0 = wrA[t+0]; wA1 = wrA[t+1]; wA2 = wrA[t+2]; wA3 = wrA[t+3];
                wB0 = wrB[t+0]; wB1 = wrB[t+1]; wB2 = wrB[t+2]; wB3 = wrB[t+3];
            }
            accA0 = dot2f(wA0, h0, accA0);
            accA1 = dot2f(wA1, h1, accA1);
            accA0 = dot2f(wA2, h2_, accA0);
            accA1 = dot2f(wA3, h3, accA1);
            accB0 = dot2f(wB0, h0, accB0);
            accB1 = dot2f(wB1, h1, accB1);
            accB0 = dot2f(wB2, h2_, accB0);
            accB1 = dot2f(wB3, h3, accB1);
        }
        float aF = zAcur + biasA + (accA0 + accA1);   // gate input(i<256)/forget
        float aS = zBcur + biasB + (accB0 + accB1);   // gate cellcand / out

        float iv = 0.f, gv = 0.f;
        if (tid < 256) {
            iv = sigm_(aF);                 // input gate
            gv = tanh_(aS);                 // cell candidate
        } else {
            act13[0][d] = sigm_(aF);        // forget gate
            act13[1][d] = sigm_(aS);        // output gate
        }
        __syncthreads();   // act13 ready; everyone done reading h_arr

        if (tid < 256) {
            float fv = act13[0][d], ov = act13[1][d];
            c_reg = fv * c_reg + iv * gv;
            float hn = ov * tanh_(c_reg);
            h_arr[d] = (_Float16)hn;
        }
        __syncthreads();   // h_arr ready for next step
        zAcur = zAn; zBcur = zBn;
    }

    if (tid < 256) {
        h_state[(size_t)b*HID + d] = (float)h_arr[d];
        c_state[(size_t)b*HID + d] = c_reg;
    }
}

// ---------------- Kernel 4: logits -> softmax -> argmax ---------------------
__global__ __launch_bounds__(64) void k_final(
    const float* __restrict__ h_state, const float* __restrict__ W_out,
    const float* __restrict__ b_out, float* __restrict__ out)
{
    int b = threadIdx.x;   // 64 threads
    float l0 = b_out[0], l1 = b_out[1];
    for (int k = 0; k < HID; ++k) {
        float h = h_state[b*HID + k];
        l0 += h * W_out[k];
        l1 += h * W_out[HID + k];
    }
    float m  = fmaxf(l0, l1);
    float e0 = expf(l0 - m), e1 = expf(l1 - m);
    float s  = e0 + e1;
    float p0 = e0 / s, p1 = e1 / s;
    out[b*2 + 0] = p0;
    out[b*2 + 1] = p1;
    out[BATCH*2 + b] = (p1 > p0) ? 1.0f : 0.0f;  // argmax, first-index tiebreak
}

// ---------------- host ------------------------------------------------------
extern "C" void kernel_launch(void* const* d_in, const int* in_sizes, int n_in,
                              void* d_out, int out_size, void* d_ws, size_t ws_size,
                              hipStream_t stream)
{
    (void)in_sizes; (void)n_in; (void)out_size;
    const float* emb   = (const float*)d_in[0];
    const float* mask  = (const float*)d_in[1];
    const int*   len   = (const int*)  d_in[2];
    const float* W_ih  = (const float*)d_in[3];
    const float* W_hh  = (const float*)d_in[4];
    const float* b_ih  = (const float*)d_in[5];
    const float* b_hh  = (const float*)d_in[6];
    const float* W_out = (const float*)d_in[7];
    const float* b_out = (const float*)d_in[8];
    float* out = (float*)d_out;

    char* p = (char*)d_ws;
    auto carve = [&](size_t bytes) -> char* {
        char* r = p;
        p += (bytes + 255) & ~(size_t)255;
        return r;
    };
    float* h_state = (float*)carve((size_t)BATCH*HID*4);
    float* c_state = (float*)carve((size_t)BATCH*HID*4);
    int*   cntb    = (int*)  carve((size_t)BATCH*4);

    size_t fixed = (size_t)(p - (char*)d_ws);
    int CT = TSTEPS;  // shrink to fit workspace
    while (CT > 64) {
        size_t lb = (((size_t)BATCH*CT*4) + 255) & ~(size_t)255;
        size_t zb = (size_t)BATCH*CT*GATES*4;
        if (fixed + lb + zb + 1024 <= ws_size) break;
        CT >>= 1;
    }
    int*   list = (int*)  carve((size_t)BATCH*CT*4);
    float* Z    = (float*)carve((size_t)BATCH*CT*GATES*4);

    int nchunks = TSTEPS / CT;
    for (int c = 0; c < nchunks; ++c) {
        int t0 = c * CT;
        int first = (c == 0) ? 1 : 0;
        hipLaunchKernelGGL(k_compact, dim3(BATCH), dim3(256), 0, stream,
                           mask, len, list, cntb, h_state, c_state,
                           t0, CT, first);
        hipLaunchKernelGGL(k_gemm, dim3(8, 1, BATCH), dim3(256), 0, stream,
                           emb, W_ih, list, cntb, Z, CT);
        hipLaunchKernelGGL(k_lstm, dim3(BATCH), dim3(512), 0, stream,
                           Z, cntb, W_hh, b_ih, b_hh,
                           h_state, c_state, CT);
    }
    hipLaunchKernelGGL(k_final, dim3(1), dim3(64), 0, stream,
                       h_state, W_out, b_out, out);
}